// Round 14
// baseline (1414.604 us; speedup 1.0000x reference)
//
#include <hip/hip_runtime.h>
#include <hip/hip_bf16.h>
#include <type_traits>

#define BB 32
#define AA 256
#define DD 512
#define HH 8
#define NLAYER 6
#define DFF 2048
#define NB 4

typedef float  f32x4_t  __attribute__((ext_vector_type(4)));
typedef short  bf16x8_t __attribute__((ext_vector_type(8)));

struct __align__(16) US8 { ushort u[8]; };

__device__ __forceinline__ ushort f2bf(float f) {
    __hip_bfloat16 h = __float2bfloat16(f);
    return *reinterpret_cast<ushort*>(&h);
}
__device__ __forceinline__ float bf2f(ushort u) {
    __hip_bfloat16 h;
    *reinterpret_cast<ushort*>(&h) = u;
    return __bfloat162float(h);
}

// async global->LDS, 16B per lane (dest linear: wave base + lane*16)
__device__ __forceinline__ void gload16(const void* g, void* l) {
    __builtin_amdgcn_global_load_lds(
        (const __attribute__((address_space(1))) void*)g,
        (__attribute__((address_space(3))) void*)l, 16, 0, 0);
}

template<int N> __device__ __forceinline__ void wait_vmcnt() {
    if constexpr      (N == 0) asm volatile("s_waitcnt vmcnt(0)" ::: "memory");
    else if constexpr (N == 1) asm volatile("s_waitcnt vmcnt(1)" ::: "memory");
    else static_assert(N == 0, "add vmcnt literal");
}
template<int N> using ic = std::integral_constant<int, N>;

// ---------------------------------------------------------------------------
__global__ __launch_bounds__(256) void embed_pe_kernel(
    const int* __restrict__ src, const float* __restrict__ embed,
    const float* __restrict__ pe, float* __restrict__ x)
{
    int t = blockIdx.x * 256 + threadIdx.x;
    int d4 = t & 127;
    int row = t >> 7;
    int a = row & 255;
    int d = d4 * 4;
    int sub = d >> 6;
    int e = d & 63;
    int tok = src[row * 8 + sub];
    float4 em = *(const float4*)&embed[tok * 64 + e];
    float4 p  = *(const float4*)&pe[a * DD + d];
    const float s = 22.627416997969522f;  // sqrt(512)
    float4 r;
    r.x = em.x * s + p.x; r.y = em.y * s + p.y;
    r.z = em.z * s + p.z; r.w = em.w * s + p.w;
    *(float4*)&x[(long long)row * DD + d] = r;
}

// ---------------------------------------------------------------------------
template<bool OB>
__global__ __launch_bounds__(256) void layernorm512_kernel(
    const float* x, const float* __restrict__ alpha,
    const float* __restrict__ beta, void* yv)
{
    const int row = blockIdx.x * 4 + (threadIdx.x >> 6);
    const int lane = threadIdx.x & 63;
    const float* xr = x + (long long)row * DD;
    float4 v0 = *(const float4*)&xr[lane * 8];
    float4 v1 = *(const float4*)&xr[lane * 8 + 4];
    float s  = v0.x + v0.y + v0.z + v0.w + v1.x + v1.y + v1.z + v1.w;
    float ss = v0.x*v0.x + v0.y*v0.y + v0.z*v0.z + v0.w*v0.w
             + v1.x*v1.x + v1.y*v1.y + v1.z*v1.z + v1.w*v1.w;
    #pragma unroll
    for (int off = 1; off < 64; off <<= 1) {
        s  += __shfl_xor(s, off, 64);
        ss += __shfl_xor(ss, off, 64);
    }
    float mu = s * (1.0f / 512.0f);
    float var = fmaxf(ss - 512.0f * mu * mu, 0.0f) * (1.0f / 511.0f);
    float inv = 1.0f / (sqrtf(var) + 1e-6f);
    float4 a0 = *(const float4*)&alpha[lane * 8];
    float4 a1 = *(const float4*)&alpha[lane * 8 + 4];
    float4 b0 = *(const float4*)&beta[lane * 8];
    float4 b1 = *(const float4*)&beta[lane * 8 + 4];
    float o0 = a0.x * (v0.x - mu) * inv + b0.x;
    float o1 = a0.y * (v0.y - mu) * inv + b0.y;
    float o2 = a0.z * (v0.z - mu) * inv + b0.z;
    float o3 = a0.w * (v0.w - mu) * inv + b0.w;
    float o4 = a1.x * (v1.x - mu) * inv + b1.x;
    float o5 = a1.y * (v1.y - mu) * inv + b1.y;
    float o6 = a1.z * (v1.z - mu) * inv + b1.z;
    float o7 = a1.w * (v1.w - mu) * inv + b1.w;
    if (OB) {
        US8 o;
        o.u[0] = f2bf(o0); o.u[1] = f2bf(o1); o.u[2] = f2bf(o2); o.u[3] = f2bf(o3);
        o.u[4] = f2bf(o4); o.u[5] = f2bf(o5); o.u[6] = f2bf(o6); o.u[7] = f2bf(o7);
        *(US8*)((ushort*)yv + (long long)row * DD + lane * 8) = o;
    } else {
        float* yr = (float*)yv + (long long)row * DD + lane * 8;
        float4 w0 = {o0, o1, o2, o3}, w1 = {o4, o5, o6, o7};
        *(float4*)yr = w0;
        *(float4*)(yr + 4) = w1;
    }
}

// ---------------------------------------------------------------------------
__global__ __launch_bounds__(256) void wtrans_kernel(
    const float* __restrict__ src, ushort* __restrict__ dst,
    int Nsz, int Ksz, long long sSrc, long long sDst)
{
    __shared__ float tile[64][65];
    src += blockIdx.z * sSrc;
    dst += blockIdx.z * sDst;
    const int n0 = blockIdx.x * 64, k0 = blockIdx.y * 64;
    const int t = threadIdx.x, col = t & 63, r4 = t >> 6;
    #pragma unroll
    for (int p = 0; p < 16; ++p) {
        int row = p * 4 + r4;
        tile[row][col] = src[(long long)(k0 + row) * Nsz + n0 + col];
    }
    __syncthreads();
    #pragma unroll
    for (int p = 0; p < 16; ++p) {
        int row = p * 4 + r4;
        dst[(long long)(n0 + row) * Ksz + k0 + col] = f2bf(tile[col][row]);
    }
}

__global__ __launch_bounds__(256) void wtrans4_kernel(
    const float* __restrict__ Wq, const float* __restrict__ Wk,
    const float* __restrict__ Wv, const float* __restrict__ Wo,
    ushort* __restrict__ Wqkvt, ushort* __restrict__ Wot)
{
    __shared__ float tile[64][65];
    const int z = blockIdx.z, layer = z >> 2, mat = z & 3;
    const float* src = (mat == 0 ? Wq : mat == 1 ? Wk : mat == 2 ? Wv : Wo)
                     + (long long)layer * 262144;
    ushort* dst = (mat < 3)
        ? Wqkvt + (long long)layer * 786432 + (long long)mat * 262144
        : Wot + (long long)layer * 262144;
    const int n0 = blockIdx.x * 64, k0 = blockIdx.y * 64;
    const int t = threadIdx.x, col = t & 63, r4 = t >> 6;
    #pragma unroll
    for (int p = 0; p < 16; ++p) {
        int row = p * 4 + r4;
        tile[row][col] = src[(long long)(k0 + row) * 512 + n0 + col];
    }
    __syncthreads();
    #pragma unroll
    for (int p = 0; p < 16; ++p) {
        int row = p * 4 + r4;
        dst[(long long)(n0 + row) * 512 + k0 + col] = f2bf(tile[col][row]);
    }
}

__global__ void concat_bias_kernel(const float* __restrict__ bq,
    const float* __restrict__ bk, const float* __restrict__ bv,
    float* __restrict__ o)
{
    int i = blockIdx.x * 256 + threadIdx.x;
    if (i >= NLAYER * 1536) return;
    int l = i / 1536, r = i % 1536;
    float v = r < 512 ? bq[l * 512 + r]
            : (r < 1024 ? bk[l * 512 + r - 512] : bv[l * 512 + r - 1024]);
    o[i] = v;
}

// ---------------------------------------------------------------------------
// Fused attention (r10-proven): 80 KB LDS, 2 blocks/CU.
__global__ __launch_bounds__(512, 4) void attn_kernel(
    const ushort* __restrict__ qk, const ushort* __restrict__ vT,
    ushort* __restrict__ Ob)
{
    __shared__ ushort Kl[256 * 64];
    __shared__ ushort Vl[64 * 256];
    __shared__ ushort Pl[8 * 16 * 64];

    const int t = threadIdx.x;
    const int bh = blockIdx.x;
    const int b = bh >> 3, h = bh & 7;
    const int w = t >> 6, lane = t & 63;
    const int lr = lane & 15, lg = lane >> 4;

    {
        const int j = t >> 3, slot = t & 7;
        const int chunk = slot ^ (j & 7);
        const ushort* srcK = qk + (long long)(b * 256 + j) * 1024 + 512 + h * 64 + chunk * 8;
        const int c = t >> 5, slv = t & 31;
        const int chv = slv ^ (c & 7);
        const ushort* srcV = vT + (long long)b * 131072 + (long long)(h * 64 + c) * 256 + chv * 8;
        #pragma unroll
        for (int r = 0; r < 4; ++r) {
            gload16(srcK + (long long)r * 64 * 1024, &Kl[(t + r * 512) * 8]);
            gload16(srcV + (long long)r * 16 * 256,  &Vl[(t + r * 512) * 8]);
        }
    }
    asm volatile("s_waitcnt vmcnt(0)" ::: "memory");
    __builtin_amdgcn_sched_barrier(0);
    __builtin_amdgcn_s_barrier();
    __builtin_amdgcn_sched_barrier(0);

    char* Pw = (char*)Pl + w * 2048;
    const char* Kc = (const char*)Kl;
    const char* Vc = (const char*)Vl;

    #pragma unroll 1
    for (int pass = 0; pass < 2; ++pass) {
        const int i0 = pass * 128 + w * 16;
        const ushort* qbase = qk + (long long)(b * 256 + i0 + lr) * 1024 + h * 64 + lg * 8;
        bf16x8_t qf0 = *(const bf16x8_t*)qbase;
        bf16x8_t qf1 = *(const bf16x8_t*)(qbase + 32);

        f32x4_t s[16];
        #pragma unroll
        for (int jf = 0; jf < 16; ++jf) s[jf] = (f32x4_t){0.f, 0.f, 0.f, 0.f};
        #pragma unroll
        for (int jf = 0; jf < 16; ++jf) {
            const int row = jf * 16 + lr;
            bf16x8_t k0 = *(const bf16x8_t*)(Kc + row * 128 + ((lg ^ (row & 7)) * 16));
            s[jf] = __builtin_amdgcn_mfma_f32_16x16x32_bf16(k0, qf0, s[jf], 0, 0, 0);
        }
        #pragma unroll
        for (int jf = 0; jf < 16; ++jf) {
            const int row = jf * 16 + lr;
            bf16x8_t k1 = *(const bf16x8_t*)(Kc + row * 128 + (((4 + lg) ^ (row & 7)) * 16));
            s[jf] = __builtin_amdgcn_mfma_f32_16x16x32_bf16(k1, qf1, s[jf], 0, 0, 0);
        }

        float m = -3.0e38f;
        #pragma unroll
        for (int jf = 0; jf < 16; ++jf)
            #pragma unroll
            for (int r = 0; r < 4; ++r) m = fmaxf(m, s[jf][r]);
        m = fmaxf(m, __shfl_xor(m, 16, 64));
        m = fmaxf(m, __shfl_xor(m, 32, 64));
        float l = 0.f;
        #pragma unroll
        for (int jf = 0; jf < 16; ++jf)
            #pragma unroll
            for (int r = 0; r < 4; ++r) {
                float e = __expf((s[jf][r] - m) * 0.125f);
                s[jf][r] = e; l += e;
            }
        l += __shfl_xor(l, 16, 64);
        l += __shfl_xor(l, 32, 64);
        const float inv = 1.0f / l;

        f32x4_t o[4];
        #pragma unroll
        for (int cf = 0; cf < 4; ++cf) o[cf] = (f32x4_t){0.f, 0.f, 0.f, 0.f};
        #pragma unroll
        for (int jq = 0; jq < 4; ++jq) {
            asm volatile("s_waitcnt lgkmcnt(0)" ::: "memory");
            __builtin_amdgcn_sched_barrier(0);
            #pragma unroll
            for (int jf4 = 0; jf4 < 4; ++jf4) {
                const int jf = jq * 4 + jf4;
                ushort4 u;
                u.x = f2bf(s[jf][0] * inv); u.y = f2bf(s[jf][1] * inv);
                u.z = f2bf(s[jf][2] * inv); u.w = f2bf(s[jf][3] * inv);
                const int off = (lr * 128 + jf4 * 32 + lg * 8) ^ ((lr & 7) << 4);
                *(ushort4*)(Pw + off) = u;
            }
            asm volatile("s_waitcnt lgkmcnt(0)" ::: "memory");
            __builtin_amdgcn_sched_barrier(0);
            #pragma unroll
            for (int ks2 = 0; ks2 < 2; ++ks2) {
                const int ks = jq * 2 + ks2;
                bf16x8_t pa = *(const bf16x8_t*)(Pw +
                    ((lr * 128 + ks2 * 64 + lg * 16) ^ ((lr & 7) << 4)));
                #pragma unroll
                for (int cf = 0; cf < 4; ++cf) {
                    const int crow = cf * 16 + lr;
                    bf16x8_t vb = *(const bf16x8_t*)(Vc + crow * 512 +
                        (((ks * 4 + lg) ^ (crow & 7)) * 16));
                    o[cf] = __builtin_amdgcn_mfma_f32_16x16x32_bf16(pa, vb, o[cf], 0, 0, 0);
                }
            }
        }
        asm volatile("s_waitcnt lgkmcnt(0)" ::: "memory");
        __builtin_amdgcn_sched_barrier(0);

        #pragma unroll
        for (int cf = 0; cf < 4; ++cf) {
            const int c = cf * 16 + lr;
            #pragma unroll
            for (int r = 0; r < 4; ++r) {
                const int i = i0 + lg * 4 + r;
                Ob[(long long)(b * 256 + i) * 512 + h * 64 + c] = f2bf(o[cf][r]);
            }
        }
    }
}

// ---------------------------------------------------------------------------
// 8-phase 256x256 GEMM, 1024 threads = 16 waves (4M x 4N), wave tile 64x64,
// acc[4][4] = 64 VGPR -> fits the 128-VGPR cap that spilled the 512-thread
// version (r11/r12). BK=64, 2 K-tile LDS slots (128 KB), 1 block/CU,
// 4 waves/SIMD. One gload16/thread per half-tile; boundary wait vmcnt(1).
template<int NTK, int OUT, bool RELU>
__global__ __launch_bounds__(1024) void gemm8p(
    const ushort* __restrict__ A, const ushort* __restrict__ B,
    const float* __restrict__ bias, void* __restrict__ Cv,
    ushort* __restrict__ C2, int lda, int ldb, int ldc, int gn)
{
    __shared__ ushort As[2][256 * 64];
    __shared__ ushort Bs[2][256 * 64];

    const int t = threadIdx.x;
    const int nwg = gridDim.x, bid = blockIdx.x;
    const int swz = (bid & 7) * (nwg >> 3) + (bid >> 3);
    const int nb = swz % gn, mb = swz / gn;
    const int m0 = mb * 256, n0 = nb * 256;

    const int trow = t >> 3;                    // 0..127
    const int tslot = (t & 7) ^ (trow & 7);
    const ushort* Ap = A + (long long)(m0 + trow) * lda + tslot * 8;
    const ushort* Bp = B + (long long)(n0 + trow) * ldb + tslot * 8;

    const int w = t >> 6, lane = t & 63;
    const int wr = w >> 2, wc = w & 3;          // 4 x 4 waves
    const int lr = lane & 15, lg = lane >> 4;

    f32x4_t acc[4][4];
    #pragma unroll
    for (int i = 0; i < 4; ++i)
        #pragma unroll
        for (int j = 0; j < 4; ++j)
            acc[i][j] = (f32x4_t){0.f, 0.f, 0.f, 0.f};

    // stage half-tile ht (0=A rows0-127, 1=A rows128-255, 2=B.h0, 3=B.h1)
    auto stage = [&](int kt, int ht) {
        const int s = kt & 1;
        const long long ko = (long long)kt * 64;
        const int half = ht & 1;
        const bool isA = ht < 2;
        const int ld = isA ? lda : ldb;
        ushort* dst = (isA ? &As[s][0] : &Bs[s][0]) + half * 8192 + t * 8;
        const ushort* src = (isA ? Ap : Bp) + ko + (long long)(half * 128) * ld;
        gload16(src, dst);
    };

    // one phase: quadrant Q of the 64x64 wave tile on K-tile kt
    auto phase = [&](auto qc, int kt, int skt, int sht, auto wvc) {
        constexpr int Q = decltype(qc)::value;
        constexpr int WV = decltype(wvc)::value;
        if (sht >= 0) stage(skt, sht);
        if constexpr (WV >= 0) wait_vmcnt<WV>();
        __builtin_amdgcn_sched_barrier(0);
        __builtin_amdgcn_s_barrier();
        __builtin_amdgcn_sched_barrier(0);
        const int s = kt & 1;
        constexpr int QM = Q >> 1, QN = Q & 1;
        bf16x8_t af[2][2], bf[2][2];
        #pragma unroll
        for (int i = 0; i < 2; ++i) {
            const int row = wr * 64 + (QM * 2 + i) * 16 + lr;
            #pragma unroll
            for (int ks = 0; ks < 2; ++ks)
                af[i][ks] = *(const bf16x8_t*)
                    &As[s][row * 64 + (((ks * 4 + lg) ^ (row & 7)) * 8)];
        }
        #pragma unroll
        for (int j = 0; j < 2; ++j) {
            const int row = wc * 64 + (QN * 2 + j) * 16 + lr;
            #pragma unroll
            for (int ks = 0; ks < 2; ++ks)
                bf[j][ks] = *(const bf16x8_t*)
                    &Bs[s][row * 64 + (((ks * 4 + lg) ^ (row & 7)) * 8)];
        }
        __builtin_amdgcn_s_setprio(1);
        #pragma unroll
        for (int i = 0; i < 2; ++i)
            #pragma unroll
            for (int j = 0; j < 2; ++j)
                #pragma unroll
                for (int ks = 0; ks < 2; ++ks)
                    acc[QM * 2 + i][QN * 2 + j] = __builtin_amdgcn_mfma_f32_16x16x32_bf16(
                        af[i][ks], bf[j][ks], acc[QM * 2 + i][QN * 2 + j], 0, 0, 0);
        __builtin_amdgcn_s_setprio(0);
        __builtin_amdgcn_sched_barrier(0);
        __builtin_amdgcn_s_barrier();
        __builtin_amdgcn_sched_barrier(0);
    };

    // prologue: fully stage K-tile 0 (slot 0) — 4 issues
    stage(0, 0); stage(0, 1); stage(0, 2); stage(0, 3);

    #pragma unroll 1
    for (int it = 0; it < NTK / 2; ++it) {
        const int kt = 2 * it;
        const bool last = (it == NTK / 2 - 1);
        // phases 0-3: compute kt, stage kt+1's half-tiles into the other slot
        phase(ic<0>{}, kt, kt + 1, 0, ic<1>{});
        phase(ic<1>{}, kt, kt + 1, 1, ic<-1>{});
        phase(ic<2>{}, kt, kt + 1, 2, ic<-1>{});
        phase(ic<3>{}, kt, kt + 1, 3, ic<-1>{});
        // phases 4-7: compute kt+1, stage kt+2 (slot kt&1, reads done @ph3)
        if (last) {
            phase(ic<0>{}, kt + 1, -1, -1, ic<0>{});
            phase(ic<1>{}, kt + 1, -1, -1, ic<-1>{});
            phase(ic<2>{}, kt + 1, -1, -1, ic<-1>{});
            phase(ic<3>{}, kt + 1, -1, -1, ic<-1>{});
        } else {
            phase(ic<0>{}, kt + 1, kt + 2, 0, ic<1>{});
            phase(ic<1>{}, kt + 1, kt + 2, 1, ic<-1>{});
            phase(ic<2>{}, kt + 1, kt + 2, 2, ic<-1>{});
            phase(ic<3>{}, kt + 1, kt + 2, 3, ic<-1>{});
        }
    }

    #pragma unroll
    for (int nf = 0; nf < 4; ++nf) {
        const int col = n0 + wc * 64 + nf * 16 + lr;
        const float bv = bias[col];
        #pragma unroll
        for (int mf = 0; mf < 4; ++mf) {
            const int row0 = m0 + wr * 64 + mf * 16 + lg * 4;
            #pragma unroll
            for (int j = 0; j < 4; ++j) {
                float vv = acc[mf][nf][j] + bv;
                if (RELU) vv = fmaxf(vv, 0.0f);
                const int row = row0 + j;
                if (OUT == 0) {
                    ((ushort*)Cv)[(long long)row * ldc + col] = f2bf(vv);
                } else {   // QKV split
                    if (col < 1024) {
                        ((ushort*)Cv)[(long long)row * 1024 + col] = f2bf(vv);
                    } else {
                        const int bq_ = row >> 8, a_ = row & 255;
                        C2[(long long)bq_ * 131072 + (long long)(col - 1024) * 256 + a_] = f2bf(vv);
                    }
                }
            }
        }
    }
}

// ---------------------------------------------------------------------------
// Narrow GEMM (r8/r9-proven): single buffer, template BK.
template<int BMt, int BNt, int BKt, int NT, int OUT, bool RELU, bool SWZ>
__global__ __launch_bounds__(256, 4) void gemm_nar(
    const ushort* __restrict__ A, const ushort* __restrict__ B,
    const float* __restrict__ bias, const float* __restrict__ res,
    void* __restrict__ Cv, ushort* __restrict__ C2,
    int lda, int ldb, int ldc, int gx)
{
    constexpr int SL  = BKt / 8;
    constexpr int RPI = 2048 / BKt;
    constexpr int AI  = BMt / RPI;
    constexpr int BI  = BNt / RPI;
    constexpr int HM = BMt / 2, HN = BNt / 2;
    constexpr int RM = HM / 16, RN = HN / 16;

    __shared__ ushort As[BMt * BKt];
    __shared__ ushort Bs[BNt * BKt];

    const int t = threadIdx.x;
    int nb, mb;
    if (SWZ) {
        const int nwg = gridDim.x, bid = blockIdx.x;
        const int swz = (bid & 7) * (nwg >> 3) + (bid >> 3);
        nb = swz % gx; mb = swz / gx;
    } else {
        nb = blockIdx.x; mb = blockIdx.y;
    }
    const int m0 = mb * BMt, n0 = nb * BNt;

    const int trow  = t / SL;
    const int tslot = (t % SL) ^ (trow & 7);
    const ushort* Ap = A + (long long)(m0 + trow) * lda + tslot * 8;
    const ushort* Bp = B + (long long)(n0 + trow) * ldb + tslot * 8;

    const int w = t >> 6, lane = t & 63;
    const int wr = w >> 1, wc = w & 1;
    const int lr = lane & 15, lg = lane >> 4;
    const int sx = lr & 7;

    f32x4_t acc[RM][RN];
    #pragma unroll
    for (int i = 0; i < RM; ++i)
        #pragma unroll
        for (int j = 0; j < RN; ++j)
            acc[i][j] = (f32x4_t){0.f, 0.f, 0.f, 0.f};

    for (int kt = 0; kt < NT; ++kt) {
        const long long ko = (long long)kt * BKt;
        #pragma unroll
        for (int i = 0; i < AI; ++i)
            gload16(Ap + ko + (long long)i * RPI * lda, &As[t * 8 + i * 2048]);
        #pragma unroll
        for (int i = 0; i < BI; ++i)
            gload16(Bp + ko + (long long)i * RPI * ldb, &Bs[t * 8 + i * 2048]);
        __syncthreads();

        #pragma unroll
        for (int kk = 0; kk < BKt / 32; ++kk) {
            bf16x8_t af[RM], bfr[RN];
            #pragma unroll
            for (int mf = 0; mf < RM; ++mf)
                af[mf] = *(const bf16x8_t*)
                    &As[(wr * HM + mf * 16 + lr) * BKt + (((kk * 4 + lg) ^ sx) * 8)];
            #pragma unroll
            for (int nf = 0; nf < RN; ++nf)
                bfr[nf] = *(const bf16x8_t*)
                    &Bs[(wc * HN + nf * 16 + lr) * BKt + (((kk * 4 + lg) ^ sx) * 8)];
            #pragma unroll
            for (int mf = 0; mf < RM; ++mf)
                #pragma unroll
                for (int nf = 0; nf < RN; ++nf)
                    acc[mf][nf] = __builtin_amdgcn_mfma_f32_16x16x32_bf16(
                        af[mf], bfr[nf], acc[mf][nf], 0, 0, 0);
        }
        __syncthreads();
    }

    #pragma unroll
    for (int nf = 0; nf < RN; ++nf) {
        const int col = n0 + wc * HN + nf * 16 + lr;
        const float bv = bias[col];
        #pragma unroll
        for (int mf = 0; mf < RM; ++mf) {
            const int row0 = m0 + wr * HM + mf * 16 + lg * 4;
            #pragma unroll
            for (int j = 0; j < 4; ++j) {
                float vv = acc[mf][nf][j] + bv;
                if (RELU) vv = fmaxf(vv, 0.0f);
                const int row = row0 + j;
                if (OUT == 0) {
                    ((ushort*)Cv)[(long long)row * ldc + col] = f2bf(vv);
                } else if (OUT == 1) {
                    const long long idx = (long long)row * ldc + col;
                    ((float*)Cv)[idx] = vv + res[idx];
                } else {
                    if (col < 1024) {
                        ((ushort*)Cv)[(long long)row * 1024 + col] = f2bf(vv);
                    } else {
                        const int bq_ = row >> 8, a_ = row & 255;
                        C2[(long long)bq_ * 131072 + (long long)(col - 1024) * 256 + a_] = f2bf(vv);
                    }
                }
            }
        }
    }
}

// ---------------------------------------------------------------------------
__global__ __launch_bounds__(256) void ln_edge_kernel(
    const float* __restrict__ x, const float* __restrict__ alpha,
    const float* __restrict__ beta, const float* __restrict__ Wfl,
    float* __restrict__ L, float* __restrict__ R)
{
    const int row = blockIdx.x * 4 + (threadIdx.x >> 6);
    const int lane = threadIdx.x & 63;
    const float* xr = x + (long long)row * DD;
    float4 v0 = *(const float4*)&xr[lane * 8];
    float4 v1 = *(const float4*)&xr[lane * 8 + 4];
    float s  = v0.x + v0.y + v0.z + v0.w + v1.x + v1.y + v1.z + v1.w;
    float ss = v0.x*v0.x + v0.y*v0.y + v0.z*v0.z + v0.w*v0.w
             + v1.x*v1.x + v1.y*v1.y + v1.z*v1.z + v1.w*v1.w;
    #pragma unroll
    for (int off = 1; off < 64; off <<= 1) {
        s  += __shfl_xor(s, off, 64);
        ss += __shfl_xor(ss, off, 64);
    }
    float mu = s * (1.0f / 512.0f);
    float var = fmaxf(ss - 512.0f * mu * mu, 0.0f) * (1.0f / 511.0f);
    float inv = 1.0f / (sqrtf(var) + 1e-6f);

    float h[8];
    {
        float4 a0 = *(const float4*)&alpha[lane * 8];
        float4 a1 = *(const float4*)&alpha[lane * 8 + 4];
        float4 b0 = *(const float4*)&beta[lane * 8];
        float4 b1 = *(const float4*)&beta[lane * 8 + 4];
        h[0] = a0.x * (v0.x - mu) * inv + b0.x;
        h[1] = a0.y * (v0.y - mu) * inv + b0.y;
        h[2] = a0.z * (v0.z - mu) * inv + b0.z;
        h[3] = a0.w * (v0.w - mu) * inv + b0.w;
        h[4] = a1.x * (v1.x - mu) * inv + b1.x;
        h[5] = a1.y * (v1.y - mu) * inv + b1.y;
        h[6] = a1.z * (v1.z - mu) * inv + b1.z;
        h[7] = a1.w * (v1.w - mu) * inv + b1.w;
    }
    float accL[NB] = {}, accR[NB] = {};
    #pragma unroll
    for (int tt = 0; tt < 8; ++tt) {
        const int e = lane * 8 + tt;
        float4 wl = *(const float4*)&Wfl[e * NB];
        float4 wr = *(const float4*)&Wfl[(DD + e) * NB];
        accL[0] = fmaf(h[tt], wl.x, accL[0]);
        accL[1] = fmaf(h[tt], wl.y, accL[1]);
        accL[2] = fmaf(h[tt], wl.z, accL[2]);
        accL[3] = fmaf(h[tt], wl.w, accL[3]);
        accR[0] = fmaf(h[tt], wr.x, accR[0]);
        accR[1] = fmaf(h[tt], wr.y, accR[1]);
        accR[2] = fmaf(h[tt], wr.z, accR[2]);
        accR[3] = fmaf(h[tt], wr.w, accR[3]);
    }
    #pragma unroll
    for (int n = 0; n < NB; ++n) {
        #pragma unroll
        for (int off = 1; off < 64; off <<= 1) {
            accL[n] += __shfl_xor(accL[n], off, 64);
            accR[n] += __shfl_xor(accR[n], off, 64);
        }
    }
    if (lane == 0) {
        #pragma unroll
        for (int n = 0; n < NB; ++n) {
            L[row * NB + n] = accL[n];
            R[row * NB + n] = accR[n];
        }
    }
}

__global__ __launch_bounds__(256) void edge_combine_kernel(
    const float* __restrict__ L, const float* __restrict__ R,
    const float* __restrict__ bfl, float* __restrict__ out)
{
    int idx = blockIdx.x * 256 + threadIdx.x;
    int j = idx & 255;
    int bi = idx >> 8;
    int b = bi >> 8;
    float4 l = *(const float4*)&L[bi * NB];
    float4 r = *(const float4*)&R[(b * 256 + j) * NB];
    float4 bf = *(const float4*)bfl;
    float4 o;
    o.x = l.x + r.x + bf.x; o.y = l.y + r.y + bf.y;
    o.z = l.z + r.z + bf.z; o.w = l.w + r.w + bf.w;
    *(float4*)&out[(long long)idx * NB] = o;
}

// ---------------------------------------------------------------------------
extern "C" void kernel_launch(void* const* d_in, const int* in_sizes, int n_in,
                              void* d_out, int out_size, void* d_ws, size_t ws_size,
                              hipStream_t stream)
{
    const int*   src   = (const int*)  d_in[0];
    const float* pe    = (const float*)d_in[3];
    const float* emb   = (const float*)d_in[4];
    const float* Wq    = (const float*)d_in[5];
    const float* Wk    = (const float*)d_in[6];
    const float* Wv    = (const float*)d_in[7];
    const float* Wo    = (const float*)d_in[8];
    const float* W1    = (const float*)d_in[9];
    const float* W2    = (const float*)d_in[10];
    const float* Wfl   = (const float*)d_in[11];
    const float* bq    = (const float*)d_in[12];
    const float* bk    = (const float*)d_in[13];
    const float* bv    = (const float*)d_in[14];
    const float* bo    = (const float*)d_in[15];
    const float* b1    = (const float*)d_in[16];
    const float* b2    = (const float*)d_in[17];
    const float* ln1_b = (const float*)d_in[18];
    const float* ln2_b = (const float*)d_in[19];
    const float* fn_b  = (const float*)d_in[20];
    const float* bfl   = (const float*)d_in[21];
    const float* ln1_a = (const float*)d_in[22];
    const float* ln2_a = (const float*)d_in[23];
    const float* fn_a  = (const float*)d_in[24];
    float* out = (float*)d_out;

    const long long ROWS = (long long)BB * AA;   // 8192
    char* p = (char*)d_ws;
    float*  x    = (float*)p;  p += ROWS * DD * 4;
    ushort* x2b  = (ushort*)p; p += ROWS * DD * 2;
    ushort* qk   = (ushort*)p;
    ushort* h1   = qk;                             // h1 aliases qk+vT+pad (32 MB)
    p += ROWS * 1024 * 2;
    ushort* vT   = (ushort*)p; p += (long long)BB * DD * AA * 2;
    p += 8 * 1024 * 1024;
    ushort* Wqkvt= (ushort*)p; p += (long long)NLAYER * 1536 * 512 * 2;
    ushort* Wot  = (ushort*)p; p += (long long)NLAYER * 512 * 512 * 2;
    ushort* W1t  = (ushort*)p; p += (long long)NLAYER * 2048 * 512 * 2;
    ushort* W2t  = (ushort*)p; p += (long long)NLAYER * 512 * 2048 * 2;
    float*  bqkv = (float*)p;  p += (long long)NLAYER * 1536 * 4;
    float*  left = (float*)p;  p += ROWS * NB * 4;
    float*  right= (float*)p;  p += ROWS * NB * 4;

    // ---- weight prep (bf16, K-major) ----
    wtrans4_kernel<<<dim3(8, 8, 24), 256, 0, stream>>>(Wq, Wk, Wv, Wo, Wqkvt, Wot);
    wtrans_kernel<<<dim3(32, 8, 6), 256, 0, stream>>>(W1, W1t, 2048, 512,  1048576LL, 1048576LL);
    wtrans_kernel<<<dim3(8, 32, 6), 256, 0, stream>>>(W2, W2t, 512,  2048, 1048576LL, 1048576LL);
    concat_bias_kernel<<<36, 256, 0, stream>>>(bq, bk, bv, bqkv);

    // ---- embed + PE ----
    embed_pe_kernel<<<4096, 256, 0, stream>>>(src, emb, pe, x);

    for (int i = 0; i < NLAYER; ++i) {
        // LN1 -> bf16
        layernorm512_kernel<true><<<2048, 256, 0, stream>>>(
            x, ln1_a + i * DD, ln1_b + i * DD, x2b);
        // fused QKV projection (8-phase 256x256, 1024 thr), V-transpose epilogue
        gemm8p<8, 2, false><<<192, 1024, 0, stream>>>(
            x2b, Wqkvt + (long long)i * 786432, bqkv + i * 1536,
            qk, vT, 512, 512, 1024, 6);
        // fused attention -> x2b
        attn_kernel<<<256, 512, 0, stream>>>(qk, vT, x2b);
        // x += O@Wo + bo : 128x64, BK=64
        gemm_nar<128, 64, 64, 8, 1, false, true><<<512, 256, 0, stream>>>(
            x2b, Wot + (long long)i * 262144, bo + i * DD, x,
            x, nullptr, 512, 512, 512, 8);
        // LN2 -> bf16
        layernorm512_kernel<true><<<2048, 256, 0, stream>>>(
            x, ln2_a + i * DD, ln2_b + i * DD, x2b);
        // h1 = relu(x2@W1 + b1): 8-phase 256x256 (1024 thr), grid 256 (1/CU)
        gemm8p<8, 0, true><<<256, 1024, 0, stream>>>(
            x2b, W1t + (long long)i * 1048576, b1 + i * DFF,
            h1, nullptr, 512, 512, 2048, 8);
        // x += h1@W2 + b2 : 64x64, BK=128
        gemm_nar<64, 64, 128, 16, 1, false, true><<<1024, 256, 0, stream>>>(
            h1, W2t + (long long)i * 1048576, b2 + i * DD, x,
            x, nullptr, 2048, 2048, 512, 8);
    }

    // fused final norm + edge heads, then combine
    ln_edge_kernel<<<2048, 256, 0, stream>>>(x, fn_a, fn_b, Wfl, left, right);
    edge_combine_kernel<<<8192, 256, 0, stream>>>(left, right, bfl, out);
}

// Round 15
// 701.327 us; speedup vs baseline: 2.0170x; 2.0170x over previous
//
#include <hip/hip_runtime.h>
#include <hip/hip_bf16.h>

#define BB 32
#define AA 256
#define DD 512
#define HH 8
#define NLAYER 6
#define DFF 2048
#define NB 4

typedef float  f32x4_t  __attribute__((ext_vector_type(4)));
typedef short  bf16x8_t __attribute__((ext_vector_type(8)));

struct __align__(16) US8 { ushort u[8]; };

__device__ __forceinline__ ushort f2bf(float f) {
    __hip_bfloat16 h = __float2bfloat16(f);
    return *reinterpret_cast<ushort*>(&h);
}
__device__ __forceinline__ float bf2f(ushort u) {
    __hip_bfloat16 h;
    *reinterpret_cast<ushort*>(&h) = u;
    return __bfloat162float(h);
}

// async global->LDS, 16B per lane (dest linear: wave base + lane*16)
__device__ __forceinline__ void gload16(const void* g, void* l) {
    __builtin_amdgcn_global_load_lds(
        (const __attribute__((address_space(1))) void*)g,
        (__attribute__((address_space(3))) void*)l, 16, 0, 0);
}

// ---------------------------------------------------------------------------
__global__ __launch_bounds__(256) void embed_pe_kernel(
    const int* __restrict__ src, const float* __restrict__ embed,
    const float* __restrict__ pe, float* __restrict__ x)
{
    int t = blockIdx.x * 256 + threadIdx.x;
    int d4 = t & 127;
    int row = t >> 7;
    int a = row & 255;
    int d = d4 * 4;
    int sub = d >> 6;
    int e = d & 63;
    int tok = src[row * 8 + sub];
    float4 em = *(const float4*)&embed[tok * 64 + e];
    float4 p  = *(const float4*)&pe[a * DD + d];
    const float s = 22.627416997969522f;  // sqrt(512)
    float4 r;
    r.x = em.x * s + p.x; r.y = em.y * s + p.y;
    r.z = em.z * s + p.z; r.w = em.w * s + p.w;
    *(float4*)&x[(long long)row * DD + d] = r;
}

// ---------------------------------------------------------------------------
template<bool OB>
__global__ __launch_bounds__(256) void layernorm512_kernel(
    const float* x, const float* __restrict__ alpha,
    const float* __restrict__ beta, void* yv)
{
    const int row = blockIdx.x * 4 + (threadIdx.x >> 6);
    const int lane = threadIdx.x & 63;
    const float* xr = x + (long long)row * DD;
    float4 v0 = *(const float4*)&xr[lane * 8];
    float4 v1 = *(const float4*)&xr[lane * 8 + 4];
    float s  = v0.x + v0.y + v0.z + v0.w + v1.x + v1.y + v1.z + v1.w;
    float ss = v0.x*v0.x + v0.y*v0.y + v0.z*v0.z + v0.w*v0.w
             + v1.x*v1.x + v1.y*v1.y + v1.z*v1.z + v1.w*v1.w;
    #pragma unroll
    for (int off = 1; off < 64; off <<= 1) {
        s  += __shfl_xor(s, off, 64);
        ss += __shfl_xor(ss, off, 64);
    }
    float mu = s * (1.0f / 512.0f);
    float var = fmaxf(ss - 512.0f * mu * mu, 0.0f) * (1.0f / 511.0f);
    float inv = 1.0f / (sqrtf(var) + 1e-6f);
    float4 a0 = *(const float4*)&alpha[lane * 8];
    float4 a1 = *(const float4*)&alpha[lane * 8 + 4];
    float4 b0 = *(const float4*)&beta[lane * 8];
    float4 b1 = *(const float4*)&beta[lane * 8 + 4];
    float o0 = a0.x * (v0.x - mu) * inv + b0.x;
    float o1 = a0.y * (v0.y - mu) * inv + b0.y;
    float o2 = a0.z * (v0.z - mu) * inv + b0.z;
    float o3 = a0.w * (v0.w - mu) * inv + b0.w;
    float o4 = a1.x * (v1.x - mu) * inv + b1.x;
    float o5 = a1.y * (v1.y - mu) * inv + b1.y;
    float o6 = a1.z * (v1.z - mu) * inv + b1.z;
    float o7 = a1.w * (v1.w - mu) * inv + b1.w;
    if (OB) {
        US8 o;
        o.u[0] = f2bf(o0); o.u[1] = f2bf(o1); o.u[2] = f2bf(o2); o.u[3] = f2bf(o3);
        o.u[4] = f2bf(o4); o.u[5] = f2bf(o5); o.u[6] = f2bf(o6); o.u[7] = f2bf(o7);
        *(US8*)((ushort*)yv + (long long)row * DD + lane * 8) = o;
    } else {
        float* yr = (float*)yv + (long long)row * DD + lane * 8;
        float4 w0 = {o0, o1, o2, o3}, w1 = {o4, o5, o6, o7};
        *(float4*)yr = w0;
        *(float4*)(yr + 4) = w1;
    }
}

// ---------------------------------------------------------------------------
// Generic weight transpose fp32[K][N] -> bf16[N][K] (for W1, W2)
__global__ __launch_bounds__(256) void wtrans_kernel(
    const float* __restrict__ src, ushort* __restrict__ dst,
    int Nsz, int Ksz, long long sSrc, long long sDst)
{
    __shared__ float tile[64][65];
    src += blockIdx.z * sSrc;
    dst += blockIdx.z * sDst;
    const int n0 = blockIdx.x * 64, k0 = blockIdx.y * 64;
    const int t = threadIdx.x, col = t & 63, r4 = t >> 6;
    #pragma unroll
    for (int p = 0; p < 16; ++p) {
        int row = p * 4 + r4;
        tile[row][col] = src[(long long)(k0 + row) * Nsz + n0 + col];
    }
    __syncthreads();
    #pragma unroll
    for (int p = 0; p < 16; ++p) {
        int row = p * 4 + r4;
        dst[(long long)(n0 + row) * Ksz + k0 + col] = f2bf(tile[col][row]);
    }
}

// Merged transpose for the four 512x512 weights: z = layer*4 + {Wq,Wk,Wv,Wo}
__global__ __launch_bounds__(256) void wtrans4_kernel(
    const float* __restrict__ Wq, const float* __restrict__ Wk,
    const float* __restrict__ Wv, const float* __restrict__ Wo,
    ushort* __restrict__ Wqkvt, ushort* __restrict__ Wot)
{
    __shared__ float tile[64][65];
    const int z = blockIdx.z, layer = z >> 2, mat = z & 3;
    const float* src = (mat == 0 ? Wq : mat == 1 ? Wk : mat == 2 ? Wv : Wo)
                     + (long long)layer * 262144;
    ushort* dst = (mat < 3)
        ? Wqkvt + (long long)layer * 786432 + (long long)mat * 262144
        : Wot + (long long)layer * 262144;
    const int n0 = blockIdx.x * 64, k0 = blockIdx.y * 64;
    const int t = threadIdx.x, col = t & 63, r4 = t >> 6;
    #pragma unroll
    for (int p = 0; p < 16; ++p) {
        int row = p * 4 + r4;
        tile[row][col] = src[(long long)(k0 + row) * 512 + n0 + col];
    }
    __syncthreads();
    #pragma unroll
    for (int p = 0; p < 16; ++p) {
        int row = p * 4 + r4;
        dst[(long long)(n0 + row) * 512 + k0 + col] = f2bf(tile[col][row]);
    }
}

__global__ void concat_bias_kernel(const float* __restrict__ bq,
    const float* __restrict__ bk, const float* __restrict__ bv,
    float* __restrict__ o)
{
    int i = blockIdx.x * 256 + threadIdx.x;
    if (i >= NLAYER * 1536) return;
    int l = i / 1536, r = i % 1536;
    float v = r < 512 ? bq[l * 512 + r]
            : (r < 1024 ? bk[l * 512 + r - 512] : bv[l * 512 + r - 1024]);
    o[i] = v;
}

// ---------------------------------------------------------------------------
// Fused attention: one block per (b,h). 8 waves, 2 passes x 16 q-rows/wave.
// LDS = K(32K) + V(32K) + P-chunks(16K) = 80 KB -> 2 blocks/CU co-residency.
__global__ __launch_bounds__(512, 4) void attn_kernel(
    const ushort* __restrict__ qk, const ushort* __restrict__ vT,
    ushort* __restrict__ Ob)
{
    __shared__ ushort Kl[256 * 64];
    __shared__ ushort Vl[64 * 256];
    __shared__ ushort Pl[8 * 16 * 64];

    const int t = threadIdx.x;
    const int bh = blockIdx.x;
    const int b = bh >> 3, h = bh & 7;
    const int w = t >> 6, lane = t & 63;
    const int lr = lane & 15, lg = lane >> 4;

    {   // stage K and V^T (pre-swizzled global source, linear LDS dest)
        const int j = t >> 3, slot = t & 7;
        const int chunk = slot ^ (j & 7);
        const ushort* srcK = qk + (long long)(b * 256 + j) * 1024 + 512 + h * 64 + chunk * 8;
        const int c = t >> 5, slv = t & 31;
        const int chv = slv ^ (c & 7);
        const ushort* srcV = vT + (long long)b * 131072 + (long long)(h * 64 + c) * 256 + chv * 8;
        #pragma unroll
        for (int r = 0; r < 4; ++r) {
            gload16(srcK + (long long)r * 64 * 1024, &Kl[(t + r * 512) * 8]);
            gload16(srcV + (long long)r * 16 * 256,  &Vl[(t + r * 512) * 8]);
        }
    }
    asm volatile("s_waitcnt vmcnt(0)" ::: "memory");
    __builtin_amdgcn_sched_barrier(0);
    __builtin_amdgcn_s_barrier();
    __builtin_amdgcn_sched_barrier(0);

    char* Pw = (char*)Pl + w * 2048;
    const char* Kc = (const char*)Kl;
    const char* Vc = (const char*)Vl;

    #pragma unroll 1
    for (int pass = 0; pass < 2; ++pass) {
        const int i0 = pass * 128 + w * 16;
        const ushort* qbase = qk + (long long)(b * 256 + i0 + lr) * 1024 + h * 64 + lg * 8;
        bf16x8_t qf0 = *(const bf16x8_t*)qbase;
        bf16x8_t qf1 = *(const bf16x8_t*)(qbase + 32);

        // S^T = K @ Q^T  (lane (lg,lr): i = i0+lr, j = jf*16 + lg*4 + r)
        f32x4_t s[16];
        #pragma unroll
        for (int jf = 0; jf < 16; ++jf) s[jf] = (f32x4_t){0.f, 0.f, 0.f, 0.f};
        #pragma unroll
        for (int jf = 0; jf < 16; ++jf) {
            const int row = jf * 16 + lr;
            bf16x8_t k0 = *(const bf16x8_t*)(Kc + row * 128 + ((lg ^ (row & 7)) * 16));
            s[jf] = __builtin_amdgcn_mfma_f32_16x16x32_bf16(k0, qf0, s[jf], 0, 0, 0);
        }
        #pragma unroll
        for (int jf = 0; jf < 16; ++jf) {
            const int row = jf * 16 + lr;
            bf16x8_t k1 = *(const bf16x8_t*)(Kc + row * 128 + (((4 + lg) ^ (row & 7)) * 16));
            s[jf] = __builtin_amdgcn_mfma_f32_16x16x32_bf16(k1, qf1, s[jf], 0, 0, 0);
        }

        // softmax over all 256 j for this lane's i
        float m = -3.0e38f;
        #pragma unroll
        for (int jf = 0; jf < 16; ++jf)
            #pragma unroll
            for (int r = 0; r < 4; ++r) m = fmaxf(m, s[jf][r]);
        m = fmaxf(m, __shfl_xor(m, 16, 64));
        m = fmaxf(m, __shfl_xor(m, 32, 64));
        float l = 0.f;
        #pragma unroll
        for (int jf = 0; jf < 16; ++jf)
            #pragma unroll
            for (int r = 0; r < 4; ++r) {
                float e = __expf((s[jf][r] - m) * 0.125f);
                s[jf][r] = e; l += e;
            }
        l += __shfl_xor(l, 16, 64);
        l += __shfl_xor(l, 32, 64);
        const float inv = 1.0f / l;

        // O = P @ V^T, j processed in 4 quarter-chunks of 64
        f32x4_t o[4];
        #pragma unroll
        for (int cf = 0; cf < 4; ++cf) o[cf] = (f32x4_t){0.f, 0.f, 0.f, 0.f};
        #pragma unroll
        for (int jq = 0; jq < 4; ++jq) {
            asm volatile("s_waitcnt lgkmcnt(0)" ::: "memory");
            __builtin_amdgcn_sched_barrier(0);
            #pragma unroll
            for (int jf4 = 0; jf4 < 4; ++jf4) {
                const int jf = jq * 4 + jf4;
                ushort4 u;
                u.x = f2bf(s[jf][0] * inv); u.y = f2bf(s[jf][1] * inv);
                u.z = f2bf(s[jf][2] * inv); u.w = f2bf(s[jf][3] * inv);
                const int off = (lr * 128 + jf4 * 32 + lg * 8) ^ ((lr & 7) << 4);
                *(ushort4*)(Pw + off) = u;
            }
            asm volatile("s_waitcnt lgkmcnt(0)" ::: "memory");
            __builtin_amdgcn_sched_barrier(0);
            #pragma unroll
            for (int ks2 = 0; ks2 < 2; ++ks2) {
                const int ks = jq * 2 + ks2;
                bf16x8_t pa = *(const bf16x8_t*)(Pw +
                    ((lr * 128 + ks2 * 64 + lg * 16) ^ ((lr & 7) << 4)));
                #pragma unroll
                for (int cf = 0; cf < 4; ++cf) {
                    const int crow = cf * 16 + lr;
                    bf16x8_t vb = *(const bf16x8_t*)(Vc + crow * 512 +
                        (((ks * 4 + lg) ^ (crow & 7)) * 16));
                    o[cf] = __builtin_amdgcn_mfma_f32_16x16x32_bf16(pa, vb, o[cf], 0, 0, 0);
                }
            }
        }
        asm volatile("s_waitcnt lgkmcnt(0)" ::: "memory");
        __builtin_amdgcn_sched_barrier(0);

        #pragma unroll
        for (int cf = 0; cf < 4; ++cf) {
            const int c = cf * 16 + lr;
            #pragma unroll
            for (int r = 0; r < 4; ++r) {
                const int i = i0 + lg * 4 + r;
                Ob[(long long)(b * 256 + i) * 512 + h * 64 + c] = f2bf(o[cf][r]);
            }
        }
    }
}

// ---------------------------------------------------------------------------
// Narrow GEMM, m97 single-buffer structure, template BK (64 or 128 elems).
// Both-side 3-bit XOR slot swizzle; 4 waves (2x2), wave tile (BMt/2)x(BNt/2).
// OUT: 0 = bf16, 1 = fp32 + residual add, 2 = QKV split (cols<1024 -> bf16 C
// at ldc=1024; cols>=1024 -> V head-transposed scatter into C2 [b][c][a]).
template<int BMt, int BNt, int BKt, int NT, int OUT, bool RELU, bool SWZ>
__global__ __launch_bounds__(256, 4) void gemm_nar(
    const ushort* __restrict__ A, const ushort* __restrict__ B,
    const float* __restrict__ bias, const float* __restrict__ res,
    void* __restrict__ Cv, ushort* __restrict__ C2,
    int lda, int ldb, int ldc, int gx)
{
    constexpr int SL  = BKt / 8;            // 16B slots per LDS row
    constexpr int RPI = 2048 / BKt;         // rows staged per issue (256 thr)
    constexpr int AI  = BMt / RPI;
    constexpr int BI  = BNt / RPI;
    constexpr int HM = BMt / 2, HN = BNt / 2;
    constexpr int RM = HM / 16, RN = HN / 16;

    __shared__ ushort As[BMt * BKt];
    __shared__ ushort Bs[BNt * BKt];

    const int t = threadIdx.x;
    int nb, mb;
    if (SWZ) {
        const int nwg = gridDim.x, bid = blockIdx.x;
        const int swz = (bid & 7) * (nwg >> 3) + (bid >> 3);
        nb = swz % gx; mb = swz / gx;
    } else {
        nb = blockIdx.x; mb = blockIdx.y;
    }
    const int m0 = mb * BMt, n0 = nb * BNt;

    const int trow  = t / SL;
    const int tslot = (t % SL) ^ (trow & 7);
    const ushort* Ap = A + (long long)(m0 + trow) * lda + tslot * 8;
    const ushort* Bp = B + (long long)(n0 + trow) * ldb + tslot * 8;

    const int w = t >> 6, lane = t & 63;
    const int wr = w >> 1, wc = w & 1;
    const int lr = lane & 15, lg = lane >> 4;
    const int sx = lr & 7;

    f32x4_t acc[RM][RN];
    #pragma unroll
    for (int i = 0; i < RM; ++i)
        #pragma unroll
        for (int j = 0; j < RN; ++j)
            acc[i][j] = (f32x4_t){0.f, 0.f, 0.f, 0.f};

    for (int kt = 0; kt < NT; ++kt) {
        const long long ko = (long long)kt * BKt;
        #pragma unroll
        for (int i = 0; i < AI; ++i)
            gload16(Ap + ko + (long long)i * RPI * lda, &As[t * 8 + i * 2048]);
        #pragma unroll
        for (int i = 0; i < BI; ++i)
            gload16(Bp + ko + (long long)i * RPI * ldb, &Bs[t * 8 + i * 2048]);
        __syncthreads();

        #pragma unroll
        for (int kk = 0; kk < BKt / 32; ++kk) {
            bf16x8_t af[RM], bfr[RN];
            #pragma unroll
            for (int mf = 0; mf < RM; ++mf)
                af[mf] = *(const bf16x8_t*)
                    &As[(wr * HM + mf * 16 + lr) * BKt + (((kk * 4 + lg) ^ sx) * 8)];
            #pragma unroll
            for (int nf = 0; nf < RN; ++nf)
                bfr[nf] = *(const bf16x8_t*)
                    &Bs[(wc * HN + nf * 16 + lr) * BKt + (((kk * 4 + lg) ^ sx) * 8)];
            #pragma unroll
            for (int mf = 0; mf < RM; ++mf)
                #pragma unroll
                for (int nf = 0; nf < RN; ++nf)
                    acc[mf][nf] = __builtin_amdgcn_mfma_f32_16x16x32_bf16(
                        af[mf], bfr[nf], acc[mf][nf], 0, 0, 0);
        }
        __syncthreads();
    }

    #pragma unroll
    for (int nf = 0; nf < RN; ++nf) {
        const int col = n0 + wc * HN + nf * 16 + lr;
        const float bv = bias[col];
        #pragma unroll
        for (int mf = 0; mf < RM; ++mf) {
            const int row0 = m0 + wr * HM + mf * 16 + lg * 4;
            #pragma unroll
            for (int j = 0; j < 4; ++j) {
                float vv = acc[mf][nf][j] + bv;
                if (RELU) vv = fmaxf(vv, 0.0f);
                const int row = row0 + j;
                if (OUT == 0) {
                    ((ushort*)Cv)[(long long)row * ldc + col] = f2bf(vv);
                } else if (OUT == 1) {
                    const long long idx = (long long)row * ldc + col;
                    ((float*)Cv)[idx] = vv + res[idx];
                } else {   // QKV split
                    if (col < 1024) {
                        ((ushort*)Cv)[(long long)row * 1024 + col] = f2bf(vv);
                    } else {
                        const int bq_ = row >> 8, a_ = row & 255;
                        C2[(long long)bq_ * 131072 + (long long)(col - 1024) * 256 + a_] = f2bf(vv);
                    }
                }
            }
        }
    }
}

// ---------------------------------------------------------------------------
// Fused final-norm + edge heads: wave per row; h never hits memory.
__global__ __launch_bounds__(256) void ln_edge_kernel(
    const float* __restrict__ x, const float* __restrict__ alpha,
    const float* __restrict__ beta, const float* __restrict__ Wfl,
    float* __restrict__ L, float* __restrict__ R)
{
    const int row = blockIdx.x * 4 + (threadIdx.x >> 6);
    const int lane = threadIdx.x & 63;
    const float* xr = x + (long long)row * DD;
    float4 v0 = *(const float4*)&xr[lane * 8];
    float4 v1 = *(const float4*)&xr[lane * 8 + 4];
    float s  = v0.x + v0.y + v0.z + v0.w + v1.x + v1.y + v1.z + v1.w;
    float ss = v0.x*v0.x + v0.y*v0.y + v0.z*v0.z + v0.w*v0.w
             + v1.x*v1.x + v1.y*v1.y + v1.z*v1.z + v1.w*v1.w;
    #pragma unroll
    for (int off = 1; off < 64; off <<= 1) {
        s  += __shfl_xor(s, off, 64);
        ss += __shfl_xor(ss, off, 64);
    }
    float mu = s * (1.0f / 512.0f);
    float var = fmaxf(ss - 512.0f * mu * mu, 0.0f) * (1.0f / 511.0f);
    float inv = 1.0f / (sqrtf(var) + 1e-6f);

    float h[8];
    {
        float4 a0 = *(const float4*)&alpha[lane * 8];
        float4 a1 = *(const float4*)&alpha[lane * 8 + 4];
        float4 b0 = *(const float4*)&beta[lane * 8];
        float4 b1 = *(const float4*)&beta[lane * 8 + 4];
        h[0] = a0.x * (v0.x - mu) * inv + b0.x;
        h[1] = a0.y * (v0.y - mu) * inv + b0.y;
        h[2] = a0.z * (v0.z - mu) * inv + b0.z;
        h[3] = a0.w * (v0.w - mu) * inv + b0.w;
        h[4] = a1.x * (v1.x - mu) * inv + b1.x;
        h[5] = a1.y * (v1.y - mu) * inv + b1.y;
        h[6] = a1.z * (v1.z - mu) * inv + b1.z;
        h[7] = a1.w * (v1.w - mu) * inv + b1.w;
    }
    float accL[NB] = {}, accR[NB] = {};
    #pragma unroll
    for (int tt = 0; tt < 8; ++tt) {
        const int e = lane * 8 + tt;
        float4 wl = *(const float4*)&Wfl[e * NB];
        float4 wr = *(const float4*)&Wfl[(DD + e) * NB];
        accL[0] = fmaf(h[tt], wl.x, accL[0]);
        accL[1] = fmaf(h[tt], wl.y, accL[1]);
        accL[2] = fmaf(h[tt], wl.z, accL[2]);
        accL[3] = fmaf(h[tt], wl.w, accL[3]);
        accR[0] = fmaf(h[tt], wr.x, accR[0]);
        accR[1] = fmaf(h[tt], wr.y, accR[1]);
        accR[2] = fmaf(h[tt], wr.z, accR[2]);
        accR[3] = fmaf(h[tt], wr.w, accR[3]);
    }
    #pragma unroll
    for (int n = 0; n < NB; ++n) {
        #pragma unroll
        for (int off = 1; off < 64; off <<= 1) {
            accL[n] += __shfl_xor(accL[n], off, 64);
            accR[n] += __shfl_xor(accR[n], off, 64);
        }
    }
    if (lane == 0) {
        #pragma unroll
        for (int n = 0; n < NB; ++n) {
            L[row * NB + n] = accL[n];
            R[row * NB + n] = accR[n];
        }
    }
}

__global__ __launch_bounds__(256) void edge_combine_kernel(
    const float* __restrict__ L, const float* __restrict__ R,
    const float* __restrict__ bfl, float* __restrict__ out)
{
    int idx = blockIdx.x * 256 + threadIdx.x;
    int j = idx & 255;
    int bi = idx >> 8;
    int b = bi >> 8;
    float4 l = *(const float4*)&L[bi * NB];
    float4 r = *(const float4*)&R[(b * 256 + j) * NB];
    float4 bf = *(const float4*)bfl;
    float4 o;
    o.x = l.x + r.x + bf.x; o.y = l.y + r.y + bf.y;
    o.z = l.z + r.z + bf.z; o.w = l.w + r.w + bf.w;
    *(float4*)&out[(long long)idx * NB] = o;
}

// ---------------------------------------------------------------------------
extern "C" void kernel_launch(void* const* d_in, const int* in_sizes, int n_in,
                              void* d_out, int out_size, void* d_ws, size_t ws_size,
                              hipStream_t stream)
{
    const int*   src   = (const int*)  d_in[0];
    const float* pe    = (const float*)d_in[3];
    const float* emb   = (const float*)d_in[4];
    const float* Wq    = (const float*)d_in[5];
    const float* Wk    = (const float*)d_in[6];
    const float* Wv    = (const float*)d_in[7];
    const float* Wo    = (const float*)d_in[8];
    const float* W1    = (const float*)d_in[9];
    const float* W2    = (const float*)d_in[10];
    const float* Wfl   = (const float*)d_in[11];
    const float* bq    = (const float*)d_in[12];
    const float* bk    = (const float*)d_in[13];
    const float* bv    = (const float*)d_in[14];
    const float* bo    = (const float*)d_in[15];
    const float* b1    = (const float*)d_in[16];
    const float* b2    = (const float*)d_in[17];
    const float* ln1_b = (const float*)d_in[18];
    const float* ln2_b = (const float*)d_in[19];
    const float* fn_b  = (const float*)d_in[20];
    const float* bfl   = (const float*)d_in[21];
    const float* ln1_a = (const float*)d_in[22];
    const float* ln2_a = (const float*)d_in[23];
    const float* fn_a  = (const float*)d_in[24];
    float* out = (float*)d_out;

    const long long ROWS = (long long)BB * AA;   // 8192
    char* p = (char*)d_ws;
    float*  x    = (float*)p;  p += ROWS * DD * 4;                 // 16 MB
    ushort* x2b  = (ushort*)p; p += ROWS * DD * 2;                 // 8 MB (LN out / attn out)
    ushort* qk   = (ushort*)p;                                     // 16 MB [row][1024]
    ushort* h1   = qk;                                             // h1 aliases qk+vT+pad (32 MB)
    p += ROWS * 1024 * 2;
    ushort* vT   = (ushort*)p; p += (long long)BB * DD * AA * 2;   // 8 MB [b][c][a]
    p += 8 * 1024 * 1024;                                          // pad so h1 fits 32 MB
    ushort* Wqkvt= (ushort*)p; p += (long long)NLAYER * 1536 * 512 * 2;
    ushort* Wot  = (ushort*)p; p += (long long)NLAYER * 512 * 512 * 2;
    ushort* W1t  = (ushort*)p; p += (long long)NLAYER * 2048 * 512 * 2;
    ushort* W2t  = (ushort*)p; p += (long long)NLAYER * 512 * 2048 * 2;
    float*  bqkv = (float*)p;  p += (long long)NLAYER * 1536 * 4;
    float*  left = (float*)p;  p += ROWS * NB * 4;
    float*  right= (float*)p;  p += ROWS * NB * 4;

    // ---- weight prep (bf16, K-major) ----
    wtrans4_kernel<<<dim3(8, 8, 24), 256, 0, stream>>>(Wq, Wk, Wv, Wo, Wqkvt, Wot);
    wtrans_kernel<<<dim3(32, 8, 6), 256, 0, stream>>>(W1, W1t, 2048, 512,  1048576LL, 1048576LL);
    wtrans_kernel<<<dim3(8, 32, 6), 256, 0, stream>>>(W2, W2t, 512,  2048, 1048576LL, 1048576LL);
    concat_bias_kernel<<<36, 256, 0, stream>>>(bq, bk, bv, bqkv);

    // ---- embed + PE ----
    embed_pe_kernel<<<4096, 256, 0, stream>>>(src, emb, pe, x);

    for (int i = 0; i < NLAYER; ++i) {
        // LN1 -> bf16
        layernorm512_kernel<true><<<2048, 256, 0, stream>>>(
            x, ln1_a + i * DD, ln1_b + i * DD, x2b);
        // fused QKV projection with V-transpose epilogue: 128x128, BK=64 (NT=8)
        gemm_nar<128, 128, 64, 8, 2, false, true><<<768, 256, 0, stream>>>(
            x2b, Wqkvt + (long long)i * 786432, bqkv + i * 1536, nullptr,
            qk, vT, 512, 512, 1024, 12);
        // fused attention (QK^T + softmax + PV) -> x2b
        attn_kernel<<<256, 512, 0, stream>>>(qk, vT, x2b);
        // x += O@Wo + bo : 128x64, BK=64 (NT=8)
        gemm_nar<128, 64, 64, 8, 1, false, true><<<512, 256, 0, stream>>>(
            x2b, Wot + (long long)i * 262144, bo + i * DD, x,
            x, nullptr, 512, 512, 512, 8);
        // LN2 -> bf16
        layernorm512_kernel<true><<<2048, 256, 0, stream>>>(
            x, ln2_a + i * DD, ln2_b + i * DD, x2b);
        // h1 = relu(x2@W1 + b1): 128x128, BK=64 (NT=8), grid 1024 (4/CU)
        gemm_nar<128, 128, 64, 8, 0, true, true><<<1024, 256, 0, stream>>>(
            x2b, W1t + (long long)i * 1048576, b1 + i * DFF, nullptr,
            h1, nullptr, 512, 512, 2048, 16);
        // x += h1@W2 + b2 : 64x64, BK=128 (NT=16), grid 1024 (4/CU)
        gemm_nar<64, 64, 128, 16, 1, false, true><<<1024, 256, 0, stream>>>(
            h1, W2t + (long long)i * 1048576, b2 + i * DD, x,
            x, nullptr, 2048, 2048, 512, 8);
    }

    // fused final norm + edge heads, then combine
    ln_edge_kernel<<<2048, 256, 0, stream>>>(x, fn_a, fn_b, Wfl, left, right);
    edge_combine_kernel<<<8192, 256, 0, stream>>>(left, right, bfl, out);
}